// Round 15
// baseline (284.457 us; speedup 1.0000x reference)
//
#include <hip/hip_runtime.h>
#include <stdint.h>

#define N_EMB 8192
#define M_TOT 16384
#define DELTA 6e-3f   // top-2 gap threshold in log2-units
#define LN_EPS 1e-5f
#define SCL 0.09016994f  // 0.0625 * log2(e): logits in log2 units

typedef _Float16 f16;
typedef f16 f16x8 __attribute__((ext_vector_type(8)));
typedef f16 f16x4 __attribute__((ext_vector_type(4)));
typedef float f32x16 __attribute__((ext_vector_type(16)));
typedef unsigned uint32x4 __attribute__((ext_vector_type(4)));

// ws layout:
// [0,4MB)  kfrag  [256 chunks][16 frags][64 lanes][8 f16]  (QK A-operand order)
// [4MB,8MB) vfrag [256 chunks][16 frags][64 lanes][8 f16]  (PV B-operand order)
// [8MB,+4) count ; [8MB+64,+64KB) list
// [9MB,10MB) part [rows][8 slices] float2
// [10MB,42MB) embd_t [256 d][8192 n] fp32 (refine transpose)
#define WS_KFRAG 0ul
#define WS_VFRAG (4ul << 20)
#define WS_COUNT (8ul << 20)
#define WS_LIST ((8ul << 20) + 64ul)
#define WS_PART (9ul << 20)
#define WS_EMBDT (10ul << 20)

#define MFMA32(a, b, c) __builtin_amdgcn_mfma_f32_32x32x16_f16(a, b, c, 0, 0, 0)
#define SBAR() __builtin_amdgcn_sched_barrier(0)

// ---------------- prep: fragment layouts (bid<256) + fp32 transpose (bid>=256) ----
__global__ __launch_bounds__(256) void prep_kernel(const float* __restrict__ embd,
                                                   f16* __restrict__ kfrag,
                                                   f16* __restrict__ vfrag,
                                                   float* __restrict__ embd_t,
                                                   unsigned* __restrict__ count) {
  const int t = threadIdx.x;
  const int bid = blockIdx.x;
  if (bid < 256) {
    if (bid == 0 && t == 0) *count = 0u;
    __shared__ f16 tile[32][272];
    const int c = bid;
    {
      const int r = t >> 3;
      const int d0 = (t & 7) * 32;
      const float4* src = (const float4*)(embd + (size_t)(c * 32 + r) * 256 + d0);
#pragma unroll
      for (int qd = 0; qd < 8; ++qd) {
        float4 v = src[qd];
        tile[r][d0 + qd * 4 + 0] = (f16)v.x;
        tile[r][d0 + qd * 4 + 1] = (f16)v.y;
        tile[r][d0 + qd * 4 + 2] = (f16)v.z;
        tile[r][d0 + qd * 4 + 3] = (f16)v.w;
      }
    }
    __syncthreads();
#pragma unroll
    for (int i = 0; i < 4; ++i) {
      const int u = t + i * 256;
      const int kc = u >> 6;
      const int l = u & 63;
      const f16x8 pack = *(const f16x8*)&tile[l & 31][kc * 16 + ((l >> 5) & 1) * 8];
      *(f16x8*)(kfrag + (size_t)c * 8192 + (size_t)u * 8) = pack;
    }
#pragma unroll
    for (int i = 0; i < 4; ++i) {
      const int u = t + i * 256;
      const int fi = u >> 6;
      const int l = u & 63;
      const int dt = fi >> 1, ks = fi & 1;
      f16x8 pack;
#pragma unroll
      for (int j = 0; j < 8; ++j)
        pack[j] = tile[ks * 16 + ((l >> 5) & 1) * 8 + j][dt * 32 + (l & 31)];
      *(f16x8*)(vfrag + (size_t)c * 8192 + (size_t)u * 8) = pack;
    }
  } else {
    __shared__ float ftile[32][257];
    const int c = bid - 256;
    {
      const int r = t >> 3;
      const int d0 = (t & 7) * 32;
      const float4* src = (const float4*)(embd + (size_t)(c * 32 + r) * 256 + d0);
#pragma unroll
      for (int q8 = 0; q8 < 8; ++q8) {
        const float4 v = src[q8];
        ftile[r][d0 + q8 * 4 + 0] = v.x;
        ftile[r][d0 + q8 * 4 + 1] = v.y;
        ftile[r][d0 + q8 * 4 + 2] = v.z;
        ftile[r][d0 + q8 * 4 + 3] = v.w;
      }
    }
    __syncthreads();
    const int r = t & 31;
    const int dh = t >> 5;
#pragma unroll
    for (int dd = 0; dd < 32; ++dd) {
      const int d = dd * 8 + dh;
      embd_t[(size_t)d * 8192 + c * 32 + r] = ftile[r][d];
    }
  }
}

// ---------------- fused: LN + flash softmax-quantize ----------------
// R13 structure; NEW: (a) S split into two independent 8-MFMA chains (S0/S1,
// summed after QK-B) to halve the dependent-MFMA critical path; (b) pacing
// barrier every 2nd chunk (drift bounded to <=2 chunks, locality preserved).
__global__ __launch_bounds__(256, 2) void fused_kernel(
    const float* __restrict__ input, const float* __restrict__ ln_w,
    const float* __restrict__ ln_b, const f16* __restrict__ kfrag,
    const f16* __restrict__ vfrag, float* __restrict__ out_q,
    float* __restrict__ out_idx, unsigned* __restrict__ count,
    int* __restrict__ list) {
  __shared__ __align__(16) char lds[36864];
  const int tid = threadIdx.x;
  const int lane = tid & 63;
  const int w = tid >> 6;  // nq quarter
  const int q = lane & 31;
  const int hi = lane >> 5;
  const int R0 = blockIdx.x * 32;

  const f16* const kfbase = kfrag + (size_t)(w * 64) * 8192 + (size_t)lane * 8;
  const f16* const vfbase = vfrag + (size_t)(w * 64) * 8192 + (size_t)lane * 8;
  const char* const qb = lds + hi * 512 + q * 16;

  f16x8 kA[8];
#pragma unroll
  for (int f = 0; f < 8; ++f) kA[f] = *(const f16x8*)(kfbase + f * 512);

  {
    const int r = tid >> 3;
    const int seg = tid & 7;
    const float* rowp = input + (size_t)(R0 + r) * 256 + seg * 32;
    float4 xv[8];
    float sm = 0.f, ssq = 0.f;
#pragma unroll
    for (int qd = 0; qd < 8; ++qd) {
      xv[qd] = ((const float4*)rowp)[qd];
      sm += xv[qd].x + xv[qd].y + xv[qd].z + xv[qd].w;
      ssq += xv[qd].x * xv[qd].x + xv[qd].y * xv[qd].y + xv[qd].z * xv[qd].z +
             xv[qd].w * xv[qd].w;
    }
    sm += __shfl_xor(sm, 1);
    sm += __shfl_xor(sm, 2);
    sm += __shfl_xor(sm, 4);
    ssq += __shfl_xor(ssq, 1);
    ssq += __shfl_xor(ssq, 2);
    ssq += __shfl_xor(ssq, 4);
    const float mean = sm * (1.f / 256.f);
    const float var = ssq * (1.f / 256.f) - mean * mean;
    const float rstd = 1.0f / sqrtf(var + LN_EPS);
#pragma unroll
    for (int qd = 0; qd < 8; ++qd) {
      const int d0 = seg * 32 + qd * 4;
      float4 w4 = *(const float4*)(ln_w + d0);
      float4 b4 = *(const float4*)(ln_b + d0);
      f16x4 hv;
      hv[0] = (f16)((((xv[qd].x - mean) * rstd) * w4.x + b4.x) * SCL);
      hv[1] = (f16)((((xv[qd].y - mean) * rstd) * w4.y + b4.y) * SCL);
      hv[2] = (f16)((((xv[qd].z - mean) * rstd) * w4.z + b4.z) * SCL);
      hv[3] = (f16)((((xv[qd].w - mean) * rstd) * w4.w + b4.w) * SCL);
      const int off = (d0 >> 4) * 1024 + ((d0 >> 3) & 1) * 512 + r * 16 + (d0 & 7) * 2;
      *(f16x4*)(lds + off) = hv;
    }
  }
  __syncthreads();

  f32x16 acc[8] = {};
  float m_run = 0.f, l_run = 0.f, mt1 = -3.0e38f, mt2 = -3.0e38f;
  int i1 = 0;

  for (int c = 0; c < 64; ++c) {
    const int nb = w * 2048 + c * 32;
    const f16* const kc_base = kfbase + (size_t)c * 8192;
    const f16* const vc_base = vfbase + (size_t)c * 8192;
    if ((c & 1) == 0) {  // pacing barrier every 2nd chunk
      SBAR();
      __builtin_amdgcn_s_barrier();
      SBAR();
    }
    f16x8 kB[8];
#pragma unroll
    for (int f = 0; f < 8; ++f) kB[f] = *(const f16x8*)(kc_base + 4096 + f * 512);
    // ---- QK: two independent 8-MFMA chains ----
    f32x16 S0 = {}, S1 = {};
#pragma unroll
    for (int kc = 0; kc < 8; ++kc) {
      const f16x8 qf = *(const f16x8*)(qb + kc * 1024);
      S0 = MFMA32(kA[kc], qf, S0);
    }
    f16x8 va[8];
#pragma unroll
    for (int dt = 0; dt < 8; ++dt) va[dt] = *(const f16x8*)(vc_base + dt * 1024);
#pragma unroll
    for (int kc = 0; kc < 8; ++kc) {
      const f16x8 qf = *(const f16x8*)(qb + (8 + kc) * 1024);
      S1 = MFMA32(kB[kc], qf, S1);
    }
    f16x8 vb[8];
#pragma unroll
    for (int dt = 0; dt < 8; ++dt)
      vb[dt] = *(const f16x8*)(vc_base + 512 + dt * 1024);
    const f32x16 S = S0 + S1;

    const float y0 = fmaxf(fmaxf(S[0], S[1]), fmaxf(S[2], S[3]));
    const float y1 = fmaxf(fmaxf(S[4], S[5]), fmaxf(S[6], S[7]));
    const float y2 = fmaxf(fmaxf(S[8], S[9]), fmaxf(S[10], S[11]));
    const float y3 = fmaxf(fmaxf(S[12], S[13]), fmaxf(S[14], S[15]));
    const float t1h = fmaxf(fmaxf(y0, y1), fmaxf(y2, y3));
    const float o1 = __shfl_xor(t1h, 32);
    const float t1max = fmaxf(t1h, o1);
    if (__any(t1max - m_run > 8.f)) {
      const float mnew = fmaxf(m_run, t1max);
      const float a = exp2f(m_run - mnew);
      l_run *= a;
      m_run = mnew;
      float av[16];
#pragma unroll
      for (int r = 0; r < 16; ++r)
        av[r] = __shfl(a, (r & 3) + 8 * (r >> 2) + hi * 4);
#pragma unroll
      for (int dt = 0; dt < 8; ++dt)
#pragma unroll
        for (int r = 0; r < 16; ++r) acc[dt][r] *= av[r];
    }
    float P[16];
#pragma unroll
    for (int r = 0; r < 16; ++r) P[r] = exp2f(S[r] - m_run);
    l_run += ((((P[0] + P[1]) + (P[2] + P[3])) + ((P[4] + P[5]) + (P[6] + P[7]))) +
              (((P[8] + P[9]) + (P[10] + P[11])) + ((P[12] + P[13]) + (P[14] + P[15]))));
    unsigned cc[8], xx[8];
#pragma unroll
    for (int i2 = 0; i2 < 8; ++i2) {
      auto pk = __builtin_amdgcn_cvt_pkrtz(P[2 * i2], P[2 * i2 + 1]);
      cc[i2] = __builtin_bit_cast(unsigned, pk);
    }
#pragma unroll
    for (int i2 = 0; i2 < 8; ++i2)
      xx[i2] = (unsigned)__shfl_xor((int)cc[i2], 32);
    uint32x4 u0, u1;
    u0[0] = hi ? xx[2] : cc[0];
    u0[1] = hi ? xx[3] : cc[1];
    u0[2] = hi ? cc[2] : xx[0];
    u0[3] = hi ? cc[3] : xx[1];
    u1[0] = hi ? xx[6] : cc[4];
    u1[1] = hi ? xx[7] : cc[5];
    u1[2] = hi ? cc[6] : xx[4];
    u1[3] = hi ? cc[7] : xx[5];
    const f16x8 pa0 = __builtin_bit_cast(f16x8, u0);
    const f16x8 pa1 = __builtin_bit_cast(f16x8, u1);

#pragma unroll
    for (int dt = 0; dt < 8; ++dt) acc[dt] = MFMA32(pa0, va[dt], acc[dt]);
    {
      const f16* p = kfbase + (size_t)((c + 1) & 63) * 8192;
#pragma unroll
      for (int f = 0; f < 8; ++f) kA[f] = *(const f16x8*)(p + f * 512);
    }
#pragma unroll
    for (int dt = 0; dt < 8; ++dt) acc[dt] = MFMA32(pa1, vb[dt], acc[dt]);

    {
      const int nbh = nb + hi * 4;
      int lih = 27;
#pragma unroll
      for (int r = 14; r >= 0; --r) {
        const int rl = (r & 3) + 8 * (r >> 2);
        lih = (S[r] == t1h) ? rl : lih;
      }
      float t2h = -3.0e38f;
#pragma unroll
      for (int r = 0; r < 16; ++r) {
        const int rl = (r & 3) + 8 * (r >> 2);
        t2h = fmaxf(t2h, (lih == rl) ? -3.0e38f : S[r]);
      }
      const int ti_h = nbh + lih;
      const float o2 = __shfl_xor(t2h, 32);
      const int oi = __shfl_xor(ti_h, 32);
      float t1, t2;
      int ti;
      if (o1 > t1h || (o1 == t1h && oi < ti_h)) {
        t1 = o1; ti = oi; t2 = fmaxf(t1h, o2);
      } else {
        t1 = t1h; ti = ti_h; t2 = fmaxf(t2h, o1);
      }
      if (t1 > mt1) { mt2 = fmaxf(mt1, t2); mt1 = t1; i1 = ti; }
      else { mt2 = fmaxf(mt2, t1); }
    }
  }

  __syncthreads();
  const float lf = l_run + __shfl_xor(l_run, 32);
  float4* statA = (float4*)(lds + 32768);
  int* statB = (int*)(lds + 32768 + 2048);
  if (hi == 0) {
    statA[w * 32 + q] = make_float4(m_run, lf, mt1, mt2);
    statB[w * 32 + q] = i1;
  }
  __syncthreads();
  const float4 s0 = statA[0 * 32 + q];
  const float4 s1 = statA[1 * 32 + q];
  const float4 s2 = statA[2 * 32 + q];
  const float4 s3 = statA[3 * 32 + q];
  const float mstar = fmaxf(fmaxf(s0.x, s1.x), fmaxf(s2.x, s3.x));
  const float lstar = s0.y * exp2f(s0.x - mstar) + s1.y * exp2f(s1.x - mstar) +
                      s2.y * exp2f(s2.x - mstar) + s3.y * exp2f(s3.x - mstar);
  const float a_self = exp2f(m_run - mstar);
  const float inv = 1.0f / lstar;
  if (w == 0 && hi == 0) {
    float wm = s0.z, wm2 = s0.w;
    int wi = statB[q];
    if (s1.z > wm) { wm2 = fmaxf(wm, s1.w); wm = s1.z; wi = statB[32 + q]; }
    else wm2 = fmaxf(wm2, s1.z);
    if (s2.z > wm) { wm2 = fmaxf(wm, s2.w); wm = s2.z; wi = statB[64 + q]; }
    else wm2 = fmaxf(wm2, s2.z);
    if (s3.z > wm) { wm2 = fmaxf(wm, s3.w); wm = s3.z; wi = statB[96 + q]; }
    else wm2 = fmaxf(wm2, s3.z);
    const int row = R0 + q;
    out_idx[row] = (float)wi;
    if (wm - wm2 <= DELTA) {
      const unsigned pos = atomicAdd(count, 1u);
      list[pos] = row;
    }
  }
  float av[16], ivr[16];
#pragma unroll
  for (int r = 0; r < 16; ++r) {
    const int qr = (r & 3) + 8 * (r >> 2) + hi * 4;
    av[r] = __shfl(a_self, qr);
    ivr[r] = __shfl(inv, qr);
  }
#pragma unroll
  for (int dt = 0; dt < 8; ++dt)
#pragma unroll
    for (int r = 0; r < 16; ++r) acc[dt][r] *= av[r];
  __syncthreads();
  float* region = (float*)lds;
#define MRG_ADDR(dt, r) (((r & 3) + 8 * (r >> 2) + hi * 4) * 256 + dt * 32 + q)
  if (w == 1) {
#pragma unroll
    for (int dt = 0; dt < 8; ++dt)
#pragma unroll
      for (int r = 0; r < 16; ++r) region[MRG_ADDR(dt, r)] = acc[dt][r];
  }
  __syncthreads();
  if (w == 0) {
#pragma unroll
    for (int dt = 0; dt < 8; ++dt)
#pragma unroll
      for (int r = 0; r < 16; ++r) acc[dt][r] += region[MRG_ADDR(dt, r)];
  }
  __syncthreads();
  if (w == 3) {
#pragma unroll
    for (int dt = 0; dt < 8; ++dt)
#pragma unroll
      for (int r = 0; r < 16; ++r) region[MRG_ADDR(dt, r)] = acc[dt][r];
  }
  __syncthreads();
  if (w == 2) {
#pragma unroll
    for (int dt = 0; dt < 8; ++dt)
#pragma unroll
      for (int r = 0; r < 16; ++r) acc[dt][r] += region[MRG_ADDR(dt, r)];
  }
  __syncthreads();
  if (w == 2) {
#pragma unroll
    for (int dt = 0; dt < 8; ++dt)
#pragma unroll
      for (int r = 0; r < 16; ++r) region[MRG_ADDR(dt, r)] = acc[dt][r];
  }
  __syncthreads();
  if (w == 0) {
#pragma unroll
    for (int dt = 0; dt < 8; ++dt)
#pragma unroll
      for (int r = 0; r < 16; ++r) {
        const int qr = (r & 3) + 8 * (r >> 2) + hi * 4;
        const float v = (acc[dt][r] + region[MRG_ADDR(dt, r)]) * ivr[r];
        out_q[(size_t)(R0 + qr) * 256 + dt * 32 + q] = v;
      }
  }
#undef MRG_ADDR
}

// ---------------- refine_part: exact fp32 argmax partials, 8 rows x 8 n-slices ----
__global__ __launch_bounds__(256) void refine_part_kernel(
    const float* __restrict__ input, const float* __restrict__ ln_w,
    const float* __restrict__ ln_b, const float* __restrict__ embd_t,
    const unsigned* __restrict__ count, const int* __restrict__ list,
    float2* __restrict__ part) {
  __shared__ float xr[8][256];
  __shared__ float redv[4][8];
  __shared__ int redn[4][8];
  const int tid = threadIdx.x;
  const unsigned cnt = *count;
  if (cnt == 0) return;
  const unsigned ntask = ((cnt + 7u) >> 3) * 8u;
  for (unsigned task = blockIdx.x; task < ntask; task += gridDim.x) {
    const unsigned grp = task >> 3;
    const int slice = (int)(task & 7u);
    __syncthreads();
    {
      const int rr = tid >> 5;
      const int sl = tid & 31;
      unsigned ridx = grp * 8u + (unsigned)rr;
      if (ridx >= cnt) ridx = cnt - 1u;
      const int row = list[ridx];
      const float* rp = input + (size_t)row * 256 + sl * 8;
      const float4 a = ((const float4*)rp)[0];
      const float4 b = ((const float4*)rp)[1];
      float sm = a.x + a.y + a.z + a.w + b.x + b.y + b.z + b.w;
      float ssq = a.x * a.x + a.y * a.y + a.z * a.z + a.w * a.w +
                  b.x * b.x + b.y * b.y + b.z * b.z + b.w * b.w;
#pragma unroll
      for (int mk = 1; mk <= 16; mk <<= 1) {
        sm += __shfl_xor(sm, mk);
        ssq += __shfl_xor(ssq, mk);
      }
      const float mean = sm * (1.f / 256.f);
      const float var = ssq * (1.f / 256.f) - mean * mean;
      const float rstd = 1.0f / sqrtf(var + LN_EPS);
      const float4 w0 = ((const float4*)(ln_w + sl * 8))[0];
      const float4 w1 = ((const float4*)(ln_w + sl * 8))[1];
      const float4 b0 = ((const float4*)(ln_b + sl * 8))[0];
      const float4 b1 = ((const float4*)(ln_b + sl * 8))[1];
      float4 o0, o1;
      o0.x = (a.x - mean) * rstd * w0.x + b0.x;
      o0.y = (a.y - mean) * rstd * w0.y + b0.y;
      o0.z = (a.z - mean) * rstd * w0.z + b0.z;
      o0.w = (a.w - mean) * rstd * w0.w + b0.w;
      o1.x = (b.x - mean) * rstd * w1.x + b1.x;
      o1.y = (b.y - mean) * rstd * w1.y + b1.y;
      o1.z = (b.z - mean) * rstd * w1.z + b1.z;
      o1.w = (b.w - mean) * rstd * w1.w + b1.w;
      *(float4*)&xr[rr][sl * 8] = o0;
      *(float4*)&xr[rr][sl * 8 + 4] = o1;
    }
    __syncthreads();
    const int n0 = slice * 1024 + tid;
    float dv[4][8] = {};
#pragma unroll 2
    for (int dq = 0; dq < 64; ++dq) {
      float4 x[8];
#pragma unroll
      for (int rr = 0; rr < 8; ++rr) x[rr] = *(const float4*)&xr[rr][dq * 4];
      const float* e0 = embd_t + (size_t)(dq * 4 + 0) * 8192 + n0;
      const float* e1 = embd_t + (size_t)(dq * 4 + 1) * 8192 + n0;
      const float* e2 = embd_t + (size_t)(dq * 4 + 2) * 8192 + n0;
      const float* e3 = embd_t + (size_t)(dq * 4 + 3) * 8192 + n0;
#pragma unroll
      for (int k = 0; k < 4; ++k) {
        const float ea = e0[k * 256];
        const float eb = e1[k * 256];
        const float ec = e2[k * 256];
        const float ed = e3[k * 256];
#pragma unroll
        for (int rr = 0; rr < 8; ++rr)
          dv[k][rr] += x[rr].x * ea + x[rr].y * eb + x[rr].z * ec + x[rr].w * ed;
      }
    }
#pragma unroll
    for (int rr = 0; rr < 8; ++rr) {
      float v = dv[0][rr];
      int nn = n0;
#pragma unroll
      for (int k = 1; k < 4; ++k)
        if (dv[k][rr] > v) { v = dv[k][rr]; nn = n0 + k * 256; }
#pragma unroll
      for (int mk = 1; mk <= 32; mk <<= 1) {
        const float ov = __shfl_xor(v, mk);
        const int on = __shfl_xor(nn, mk);
        if (ov > v || (ov == v && on < nn)) { v = ov; nn = on; }
      }
      if ((tid & 63) == 0) {
        redv[tid >> 6][rr] = v;
        redn[tid >> 6][rr] = nn;
      }
    }
    __syncthreads();
    if (tid < 8) {
      const unsigned ridx = grp * 8u + (unsigned)tid;
      if (ridx < cnt) {
        float v = redv[0][tid];
        int nn = redn[0][tid];
#pragma unroll
        for (int wv = 1; wv < 4; ++wv) {
          const float ov = redv[wv][tid];
          const int on = redn[wv][tid];
          if (ov > v || (ov == v && on < nn)) { v = ov; nn = on; }
        }
        part[ridx * 8u + (unsigned)slice] = make_float2(v, (float)nn);
      }
    }
  }
}

// ---------------- refine_merge: fold 8 slice partials per flagged row ----------------
__global__ __launch_bounds__(256) void refine_merge_kernel(
    float* __restrict__ out_idx, const unsigned* __restrict__ count,
    const int* __restrict__ list, const float2* __restrict__ part) {
  const unsigned cnt = *count;
  for (unsigned i = blockIdx.x * 256u + threadIdx.x; i < cnt;
       i += gridDim.x * 256u) {
    float v = -3.0e38f;
    int nn = 0;
#pragma unroll
    for (int s = 0; s < 8; ++s) {
      const float2 p = part[i * 8u + (unsigned)s];
      const int on = (int)p.y;
      if (p.x > v || (p.x == v && on < nn)) { v = p.x; nn = on; }
    }
    out_idx[list[i]] = (float)nn;
  }
}

extern "C" void kernel_launch(void* const* d_in, const int* in_sizes, int n_in,
                              void* d_out, int out_size, void* d_ws,
                              size_t ws_size, hipStream_t stream) {
  (void)in_sizes;
  (void)n_in;
  (void)out_size;
  (void)ws_size;
  const float* input = (const float*)d_in[0];
  const float* ln_w = (const float*)d_in[1];
  const float* ln_b = (const float*)d_in[2];
  const float* embd = (const float*)d_in[3];
  float* out_q = (float*)d_out;
  float* out_idx = out_q + (size_t)M_TOT * 256;
  char* ws = (char*)d_ws;
  f16* kfrag = (f16*)(ws + WS_KFRAG);
  f16* vfrag = (f16*)(ws + WS_VFRAG);
  unsigned* count = (unsigned*)(ws + WS_COUNT);
  int* list = (int*)(ws + WS_LIST);
  float2* part = (float2*)(ws + WS_PART);
  float* embd_t = (float*)(ws + WS_EMBDT);

  prep_kernel<<<512, 256, 0, stream>>>(embd, kfrag, vfrag, embd_t, count);
  fused_kernel<<<512, 256, 0, stream>>>(input, ln_w, ln_b, kfrag, vfrag,
                                        out_q, out_idx, count, list);
  refine_part_kernel<<<256, 256, 0, stream>>>(input, ln_w, ln_b, embd_t,
                                              count, list, part);
  refine_merge_kernel<<<16, 256, 0, stream>>>(out_idx, count, list, part);
}

// Round 16
// 279.639 us; speedup vs baseline: 1.0172x; 1.0172x over previous
//
#include <hip/hip_runtime.h>
#include <stdint.h>

#define N_EMB 8192
#define M_TOT 16384
#define DELTA 6e-3f   // top-2 gap threshold in log2-units
#define LN_EPS 1e-5f
#define SCL 0.09016994f  // 0.0625 * log2(e): logits in log2 units

typedef _Float16 f16;
typedef f16 f16x8 __attribute__((ext_vector_type(8)));
typedef f16 f16x4 __attribute__((ext_vector_type(4)));
typedef float f32x16 __attribute__((ext_vector_type(16)));
typedef unsigned uint32x4 __attribute__((ext_vector_type(4)));

// ws layout:
// [0,4MB)  kfrag  [256 chunks][16 frags][64 lanes][8 f16]  (QK A-operand order)
// [4MB,8MB) vfrag [256 chunks][16 frags][64 lanes][8 f16]  (PV B-operand order)
// [8MB,+4) count ; [8MB+64,+64KB) list
// [9MB,10MB) part [rows][8 slices] float2
// [10MB,42MB) embd_t [256 d][8192 n] fp32 (refine transpose)
#define WS_KFRAG 0ul
#define WS_VFRAG (4ul << 20)
#define WS_COUNT (8ul << 20)
#define WS_LIST ((8ul << 20) + 64ul)
#define WS_PART (9ul << 20)
#define WS_EMBDT (10ul << 20)

#define MFMA32(a, b, c) __builtin_amdgcn_mfma_f32_32x32x16_f16(a, b, c, 0, 0, 0)
#define SBAR() __builtin_amdgcn_sched_barrier(0)

// ---------------- prep: fragment layouts (bid<256) + fp32 transpose (bid>=256) ----
__global__ __launch_bounds__(256) void prep_kernel(const float* __restrict__ embd,
                                                   f16* __restrict__ kfrag,
                                                   f16* __restrict__ vfrag,
                                                   float* __restrict__ embd_t,
                                                   unsigned* __restrict__ count) {
  const int t = threadIdx.x;
  const int bid = blockIdx.x;
  if (bid < 256) {
    if (bid == 0 && t == 0) *count = 0u;
    __shared__ f16 tile[32][272];
    const int c = bid;
    {
      const int r = t >> 3;
      const int d0 = (t & 7) * 32;
      const float4* src = (const float4*)(embd + (size_t)(c * 32 + r) * 256 + d0);
#pragma unroll
      for (int qd = 0; qd < 8; ++qd) {
        float4 v = src[qd];
        tile[r][d0 + qd * 4 + 0] = (f16)v.x;
        tile[r][d0 + qd * 4 + 1] = (f16)v.y;
        tile[r][d0 + qd * 4 + 2] = (f16)v.z;
        tile[r][d0 + qd * 4 + 3] = (f16)v.w;
      }
    }
    __syncthreads();
#pragma unroll
    for (int i = 0; i < 4; ++i) {
      const int u = t + i * 256;
      const int kc = u >> 6;
      const int l = u & 63;
      const f16x8 pack = *(const f16x8*)&tile[l & 31][kc * 16 + ((l >> 5) & 1) * 8];
      *(f16x8*)(kfrag + (size_t)c * 8192 + (size_t)u * 8) = pack;
    }
#pragma unroll
    for (int i = 0; i < 4; ++i) {
      const int u = t + i * 256;
      const int fi = u >> 6;
      const int l = u & 63;
      const int dt = fi >> 1, ks = fi & 1;
      f16x8 pack;
#pragma unroll
      for (int j = 0; j < 8; ++j)
        pack[j] = tile[ks * 16 + ((l >> 5) & 1) * 8 + j][dt * 32 + (l & 31)];
      *(f16x8*)(vfrag + (size_t)c * 8192 + (size_t)u * 8) = pack;
    }
  } else {
    __shared__ float ftile[32][257];
    const int c = bid - 256;
    {
      const int r = t >> 3;
      const int d0 = (t & 7) * 32;
      const float4* src = (const float4*)(embd + (size_t)(c * 32 + r) * 256 + d0);
#pragma unroll
      for (int q8 = 0; q8 < 8; ++q8) {
        const float4 v = src[q8];
        ftile[r][d0 + q8 * 4 + 0] = v.x;
        ftile[r][d0 + q8 * 4 + 1] = v.y;
        ftile[r][d0 + q8 * 4 + 2] = v.z;
        ftile[r][d0 + q8 * 4 + 3] = v.w;
      }
    }
    __syncthreads();
    const int r = t & 31;
    const int dh = t >> 5;
#pragma unroll
    for (int dd = 0; dd < 32; ++dd) {
      const int d = dd * 8 + dh;
      embd_t[(size_t)d * 8192 + c * 32 + r] = ftile[r][d];
    }
  }
}

// ---------------- fused: LN + flash softmax-quantize (R14 base) ----------------
// Single S chain, one pacing barrier per chunk (R13/R14-proven). NEW vs R14:
// l-sum computed in the MFMA shadow from the live pa0/pa1 f16 fragments
// (hi0 lane covers n-slots {0-7,16-23}, hi1 {8-15,24-31}; epilogue cross-half
// add completes the row sum) — removes the 16-wide l-tree from the pre-PV
// critical path at zero register cost.
__global__ __launch_bounds__(256, 2) void fused_kernel(
    const float* __restrict__ input, const float* __restrict__ ln_w,
    const float* __restrict__ ln_b, const f16* __restrict__ kfrag,
    const f16* __restrict__ vfrag, float* __restrict__ out_q,
    float* __restrict__ out_idx, unsigned* __restrict__ count,
    int* __restrict__ list) {
  __shared__ __align__(16) char lds[36864];
  const int tid = threadIdx.x;
  const int lane = tid & 63;
  const int w = tid >> 6;  // nq quarter
  const int q = lane & 31;
  const int hi = lane >> 5;
  const int R0 = blockIdx.x * 32;

  const f16* const kfbase = kfrag + (size_t)(w * 64) * 8192 + (size_t)lane * 8;
  const f16* const vfbase = vfrag + (size_t)(w * 64) * 8192 + (size_t)lane * 8;
  const char* const qb = lds + hi * 512 + q * 16;

  f16x8 kA[8];
#pragma unroll
  for (int f = 0; f < 8; ++f) kA[f] = *(const f16x8*)(kfbase + f * 512);

  {
    const int r = tid >> 3;
    const int seg = tid & 7;
    const float* rowp = input + (size_t)(R0 + r) * 256 + seg * 32;
    float4 xv[8];
    float sm = 0.f, ssq = 0.f;
#pragma unroll
    for (int qd = 0; qd < 8; ++qd) {
      xv[qd] = ((const float4*)rowp)[qd];
      sm += xv[qd].x + xv[qd].y + xv[qd].z + xv[qd].w;
      ssq += xv[qd].x * xv[qd].x + xv[qd].y * xv[qd].y + xv[qd].z * xv[qd].z +
             xv[qd].w * xv[qd].w;
    }
    sm += __shfl_xor(sm, 1);
    sm += __shfl_xor(sm, 2);
    sm += __shfl_xor(sm, 4);
    ssq += __shfl_xor(ssq, 1);
    ssq += __shfl_xor(ssq, 2);
    ssq += __shfl_xor(ssq, 4);
    const float mean = sm * (1.f / 256.f);
    const float var = ssq * (1.f / 256.f) - mean * mean;
    const float rstd = 1.0f / sqrtf(var + LN_EPS);
#pragma unroll
    for (int qd = 0; qd < 8; ++qd) {
      const int d0 = seg * 32 + qd * 4;
      float4 w4 = *(const float4*)(ln_w + d0);
      float4 b4 = *(const float4*)(ln_b + d0);
      f16x4 hv;
      hv[0] = (f16)((((xv[qd].x - mean) * rstd) * w4.x + b4.x) * SCL);
      hv[1] = (f16)((((xv[qd].y - mean) * rstd) * w4.y + b4.y) * SCL);
      hv[2] = (f16)((((xv[qd].z - mean) * rstd) * w4.z + b4.z) * SCL);
      hv[3] = (f16)((((xv[qd].w - mean) * rstd) * w4.w + b4.w) * SCL);
      const int off = (d0 >> 4) * 1024 + ((d0 >> 3) & 1) * 512 + r * 16 + (d0 & 7) * 2;
      *(f16x4*)(lds + off) = hv;
    }
  }
  __syncthreads();

  f32x16 acc[8] = {};
  float m_run = 0.f, l_run = 0.f, mt1 = -3.0e38f, mt2 = -3.0e38f;
  int i1 = 0;

  for (int c = 0; c < 64; ++c) {
    const int nb = w * 2048 + c * 32;
    const f16* const kc_base = kfbase + (size_t)c * 8192;
    const f16* const vc_base = vfbase + (size_t)c * 8192;
    SBAR();
    __builtin_amdgcn_s_barrier();
    SBAR();
    f16x8 kB[8];
#pragma unroll
    for (int f = 0; f < 8; ++f) kB[f] = *(const f16x8*)(kc_base + 4096 + f * 512);
    f32x16 S = {};
#pragma unroll
    for (int kc = 0; kc < 8; ++kc) {
      const f16x8 qf = *(const f16x8*)(qb + kc * 1024);
      S = MFMA32(kA[kc], qf, S);
    }
    f16x8 va[8];
#pragma unroll
    for (int dt = 0; dt < 8; ++dt) va[dt] = *(const f16x8*)(vc_base + dt * 1024);
#pragma unroll
    for (int kc = 0; kc < 8; ++kc) {
      const f16x8 qf = *(const f16x8*)(qb + (8 + kc) * 1024);
      S = MFMA32(kB[kc], qf, S);
    }
    f16x8 vb[8];
#pragma unroll
    for (int dt = 0; dt < 8; ++dt)
      vb[dt] = *(const f16x8*)(vc_base + 512 + dt * 1024);

    const float y0 = fmaxf(fmaxf(S[0], S[1]), fmaxf(S[2], S[3]));
    const float y1 = fmaxf(fmaxf(S[4], S[5]), fmaxf(S[6], S[7]));
    const float y2 = fmaxf(fmaxf(S[8], S[9]), fmaxf(S[10], S[11]));
    const float y3 = fmaxf(fmaxf(S[12], S[13]), fmaxf(S[14], S[15]));
    const float t1h = fmaxf(fmaxf(y0, y1), fmaxf(y2, y3));
    const float o1 = __shfl_xor(t1h, 32);
    const float t1max = fmaxf(t1h, o1);
    if (__any(t1max - m_run > 8.f)) {
      const float mnew = fmaxf(m_run, t1max);
      const float a = exp2f(m_run - mnew);
      l_run *= a;
      m_run = mnew;
      float av[16];
#pragma unroll
      for (int r = 0; r < 16; ++r)
        av[r] = __shfl(a, (r & 3) + 8 * (r >> 2) + hi * 4);
#pragma unroll
      for (int dt = 0; dt < 8; ++dt)
#pragma unroll
        for (int r = 0; r < 16; ++r) acc[dt][r] *= av[r];
    }
    float P[16];
#pragma unroll
    for (int r = 0; r < 16; ++r) P[r] = exp2f(S[r] - m_run);
    unsigned cc[8], xx[8];
#pragma unroll
    for (int i2 = 0; i2 < 8; ++i2) {
      auto pk = __builtin_amdgcn_cvt_pkrtz(P[2 * i2], P[2 * i2 + 1]);
      cc[i2] = __builtin_bit_cast(unsigned, pk);
    }
#pragma unroll
    for (int i2 = 0; i2 < 8; ++i2)
      xx[i2] = (unsigned)__shfl_xor((int)cc[i2], 32);
    uint32x4 u0, u1;
    u0[0] = hi ? xx[2] : cc[0];
    u0[1] = hi ? xx[3] : cc[1];
    u0[2] = hi ? cc[2] : xx[0];
    u0[3] = hi ? cc[3] : xx[1];
    u1[0] = hi ? xx[6] : cc[4];
    u1[1] = hi ? xx[7] : cc[5];
    u1[2] = hi ? cc[6] : xx[4];
    u1[3] = hi ? cc[7] : xx[5];
    const f16x8 pa0 = __builtin_bit_cast(f16x8, u0);
    const f16x8 pa1 = __builtin_bit_cast(f16x8, u1);

#pragma unroll
    for (int dt = 0; dt < 8; ++dt) acc[dt] = MFMA32(pa0, va[dt], acc[dt]);
    {
      const f16* p = kfbase + (size_t)((c + 1) & 63) * 8192;
#pragma unroll
      for (int f = 0; f < 8; ++f) kA[f] = *(const f16x8*)(p + f * 512);
    }
#pragma unroll
    for (int dt = 0; dt < 8; ++dt) acc[dt] = MFMA32(pa1, vb[dt], acc[dt]);

    // ---- shadow bookkeeping (hidden under MFMAs): l-sum from pa + top-2 ----
    {
      float ls = 0.f;
#pragma unroll
      for (int j = 0; j < 8; ++j) ls += (float)pa0[j] + (float)pa1[j];
      l_run += ls;

      const int nbh = nb + hi * 4;
      int lih = 27;
#pragma unroll
      for (int r = 14; r >= 0; --r) {
        const int rl = (r & 3) + 8 * (r >> 2);
        lih = (S[r] == t1h) ? rl : lih;
      }
      float t2h = -3.0e38f;
#pragma unroll
      for (int r = 0; r < 16; ++r) {
        const int rl = (r & 3) + 8 * (r >> 2);
        t2h = fmaxf(t2h, (lih == rl) ? -3.0e38f : S[r]);
      }
      const int ti_h = nbh + lih;
      const float o2 = __shfl_xor(t2h, 32);
      const int oi = __shfl_xor(ti_h, 32);
      float t1, t2;
      int ti;
      if (o1 > t1h || (o1 == t1h && oi < ti_h)) {
        t1 = o1; ti = oi; t2 = fmaxf(t1h, o2);
      } else {
        t1 = t1h; ti = ti_h; t2 = fmaxf(t2h, o1);
      }
      if (t1 > mt1) { mt2 = fmaxf(mt1, t2); mt1 = t1; i1 = ti; }
      else { mt2 = fmaxf(mt2, t1); }
    }
  }

  __syncthreads();
  const float lf = l_run + __shfl_xor(l_run, 32);
  float4* statA = (float4*)(lds + 32768);
  int* statB = (int*)(lds + 32768 + 2048);
  if (hi == 0) {
    statA[w * 32 + q] = make_float4(m_run, lf, mt1, mt2);
    statB[w * 32 + q] = i1;
  }
  __syncthreads();
  const float4 s0 = statA[0 * 32 + q];
  const float4 s1 = statA[1 * 32 + q];
  const float4 s2 = statA[2 * 32 + q];
  const float4 s3 = statA[3 * 32 + q];
  const float mstar = fmaxf(fmaxf(s0.x, s1.x), fmaxf(s2.x, s3.x));
  const float lstar = s0.y * exp2f(s0.x - mstar) + s1.y * exp2f(s1.x - mstar) +
                      s2.y * exp2f(s2.x - mstar) + s3.y * exp2f(s3.x - mstar);
  const float a_self = exp2f(m_run - mstar);
  const float inv = 1.0f / lstar;
  if (w == 0 && hi == 0) {
    float wm = s0.z, wm2 = s0.w;
    int wi = statB[q];
    if (s1.z > wm) { wm2 = fmaxf(wm, s1.w); wm = s1.z; wi = statB[32 + q]; }
    else wm2 = fmaxf(wm2, s1.z);
    if (s2.z > wm) { wm2 = fmaxf(wm, s2.w); wm = s2.z; wi = statB[64 + q]; }
    else wm2 = fmaxf(wm2, s2.z);
    if (s3.z > wm) { wm2 = fmaxf(wm, s3.w); wm = s3.z; wi = statB[96 + q]; }
    else wm2 = fmaxf(wm2, s3.z);
    const int row = R0 + q;
    out_idx[row] = (float)wi;
    if (wm - wm2 <= DELTA) {
      const unsigned pos = atomicAdd(count, 1u);
      list[pos] = row;
    }
  }
  float av[16], ivr[16];
#pragma unroll
  for (int r = 0; r < 16; ++r) {
    const int qr = (r & 3) + 8 * (r >> 2) + hi * 4;
    av[r] = __shfl(a_self, qr);
    ivr[r] = __shfl(inv, qr);
  }
#pragma unroll
  for (int dt = 0; dt < 8; ++dt)
#pragma unroll
    for (int r = 0; r < 16; ++r) acc[dt][r] *= av[r];
  __syncthreads();
  float* region = (float*)lds;
#define MRG_ADDR(dt, r) (((r & 3) + 8 * (r >> 2) + hi * 4) * 256 + dt * 32 + q)
  if (w == 1) {
#pragma unroll
    for (int dt = 0; dt < 8; ++dt)
#pragma unroll
      for (int r = 0; r < 16; ++r) region[MRG_ADDR(dt, r)] = acc[dt][r];
  }
  __syncthreads();
  if (w == 0) {
#pragma unroll
    for (int dt = 0; dt < 8; ++dt)
#pragma unroll
      for (int r = 0; r < 16; ++r) acc[dt][r] += region[MRG_ADDR(dt, r)];
  }
  __syncthreads();
  if (w == 3) {
#pragma unroll
    for (int dt = 0; dt < 8; ++dt)
#pragma unroll
      for (int r = 0; r < 16; ++r) region[MRG_ADDR(dt, r)] = acc[dt][r];
  }
  __syncthreads();
  if (w == 2) {
#pragma unroll
    for (int dt = 0; dt < 8; ++dt)
#pragma unroll
      for (int r = 0; r < 16; ++r) acc[dt][r] += region[MRG_ADDR(dt, r)];
  }
  __syncthreads();
  if (w == 2) {
#pragma unroll
    for (int dt = 0; dt < 8; ++dt)
#pragma unroll
      for (int r = 0; r < 16; ++r) region[MRG_ADDR(dt, r)] = acc[dt][r];
  }
  __syncthreads();
  if (w == 0) {
#pragma unroll
    for (int dt = 0; dt < 8; ++dt)
#pragma unroll
      for (int r = 0; r < 16; ++r) {
        const int qr = (r & 3) + 8 * (r >> 2) + hi * 4;
        const float v = (acc[dt][r] + region[MRG_ADDR(dt, r)]) * ivr[r];
        out_q[(size_t)(R0 + qr) * 256 + dt * 32 + q] = v;
      }
  }
#undef MRG_ADDR
}

// ---------------- refine_part: exact fp32 argmax partials, 8 rows x 8 n-slices ----
__global__ __launch_bounds__(256) void refine_part_kernel(
    const float* __restrict__ input, const float* __restrict__ ln_w,
    const float* __restrict__ ln_b, const float* __restrict__ embd_t,
    const unsigned* __restrict__ count, const int* __restrict__ list,
    float2* __restrict__ part) {
  __shared__ float xr[8][256];
  __shared__ float redv[4][8];
  __shared__ int redn[4][8];
  const int tid = threadIdx.x;
  const unsigned cnt = *count;
  if (cnt == 0) return;
  const unsigned ntask = ((cnt + 7u) >> 3) * 8u;
  for (unsigned task = blockIdx.x; task < ntask; task += gridDim.x) {
    const unsigned grp = task >> 3;
    const int slice = (int)(task & 7u);
    __syncthreads();
    {
      const int rr = tid >> 5;
      const int sl = tid & 31;
      unsigned ridx = grp * 8u + (unsigned)rr;
      if (ridx >= cnt) ridx = cnt - 1u;
      const int row = list[ridx];
      const float* rp = input + (size_t)row * 256 + sl * 8;
      const float4 a = ((const float4*)rp)[0];
      const float4 b = ((const float4*)rp)[1];
      float sm = a.x + a.y + a.z + a.w + b.x + b.y + b.z + b.w;
      float ssq = a.x * a.x + a.y * a.y + a.z * a.z + a.w * a.w +
                  b.x * b.x + b.y * b.y + b.z * b.z + b.w * b.w;
#pragma unroll
      for (int mk = 1; mk <= 16; mk <<= 1) {
        sm += __shfl_xor(sm, mk);
        ssq += __shfl_xor(ssq, mk);
      }
      const float mean = sm * (1.f / 256.f);
      const float var = ssq * (1.f / 256.f) - mean * mean;
      const float rstd = 1.0f / sqrtf(var + LN_EPS);
      const float4 w0 = ((const float4*)(ln_w + sl * 8))[0];
      const float4 w1 = ((const float4*)(ln_w + sl * 8))[1];
      const float4 b0 = ((const float4*)(ln_b + sl * 8))[0];
      const float4 b1 = ((const float4*)(ln_b + sl * 8))[1];
      float4 o0, o1;
      o0.x = (a.x - mean) * rstd * w0.x + b0.x;
      o0.y = (a.y - mean) * rstd * w0.y + b0.y;
      o0.z = (a.z - mean) * rstd * w0.z + b0.z;
      o0.w = (a.w - mean) * rstd * w0.w + b0.w;
      o1.x = (b.x - mean) * rstd * w1.x + b1.x;
      o1.y = (b.y - mean) * rstd * w1.y + b1.y;
      o1.z = (b.z - mean) * rstd * w1.z + b1.z;
      o1.w = (b.w - mean) * rstd * w1.w + b1.w;
      *(float4*)&xr[rr][sl * 8] = o0;
      *(float4*)&xr[rr][sl * 8 + 4] = o1;
    }
    __syncthreads();
    const int n0 = slice * 1024 + tid;
    float dv[4][8] = {};
#pragma unroll 2
    for (int dq = 0; dq < 64; ++dq) {
      float4 x[8];
#pragma unroll
      for (int rr = 0; rr < 8; ++rr) x[rr] = *(const float4*)&xr[rr][dq * 4];
      const float* e0 = embd_t + (size_t)(dq * 4 + 0) * 8192 + n0;
      const float* e1 = embd_t + (size_t)(dq * 4 + 1) * 8192 + n0;
      const float* e2 = embd_t + (size_t)(dq * 4 + 2) * 8192 + n0;
      const float* e3 = embd_t + (size_t)(dq * 4 + 3) * 8192 + n0;
#pragma unroll
      for (int k = 0; k < 4; ++k) {
        const float ea = e0[k * 256];
        const float eb = e1[k * 256];
        const float ec = e2[k * 256];
        const float ed = e3[k * 256];
#pragma unroll
        for (int rr = 0; rr < 8; ++rr)
          dv[k][rr] += x[rr].x * ea + x[rr].y * eb + x[rr].z * ec + x[rr].w * ed;
      }
    }
#pragma unroll
    for (int rr = 0; rr < 8; ++rr) {
      float v = dv[0][rr];
      int nn = n0;
#pragma unroll
      for (int k = 1; k < 4; ++k)
        if (dv[k][rr] > v) { v = dv[k][rr]; nn = n0 + k * 256; }
#pragma unroll
      for (int mk = 1; mk <= 32; mk <<= 1) {
        const float ov = __shfl_xor(v, mk);
        const int on = __shfl_xor(nn, mk);
        if (ov > v || (ov == v && on < nn)) { v = ov; nn = on; }
      }
      if ((tid & 63) == 0) {
        redv[tid >> 6][rr] = v;
        redn[tid >> 6][rr] = nn;
      }
    }
    __syncthreads();
    if (tid < 8) {
      const unsigned ridx = grp * 8u + (unsigned)tid;
      if (ridx < cnt) {
        float v = redv[0][tid];
        int nn = redn[0][tid];
#pragma unroll
        for (int wv = 1; wv < 4; ++wv) {
          const float ov = redv[wv][tid];
          const int on = redn[wv][tid];
          if (ov > v || (ov == v && on < nn)) { v = ov; nn = on; }
        }
        part[ridx * 8u + (unsigned)slice] = make_float2(v, (float)nn);
      }
    }
  }
}

// ---------------- refine_merge: fold 8 slice partials per flagged row ----------------
__global__ __launch_bounds__(256) void refine_merge_kernel(
    float* __restrict__ out_idx, const unsigned* __restrict__ count,
    const int* __restrict__ list, const float2* __restrict__ part) {
  const unsigned cnt = *count;
  for (unsigned i = blockIdx.x * 256u + threadIdx.x; i < cnt;
       i += gridDim.x * 256u) {
    float v = -3.0e38f;
    int nn = 0;
#pragma unroll
    for (int s = 0; s < 8; ++s) {
      const float2 p = part[i * 8u + (unsigned)s];
      const int on = (int)p.y;
      if (p.x > v || (p.x == v && on < nn)) { v = p.x; nn = on; }
    }
    out_idx[list[i]] = (float)nn;
  }
}

extern "C" void kernel_launch(void* const* d_in, const int* in_sizes, int n_in,
                              void* d_out, int out_size, void* d_ws,
                              size_t ws_size, hipStream_t stream) {
  (void)in_sizes;
  (void)n_in;
  (void)out_size;
  (void)ws_size;
  const float* input = (const float*)d_in[0];
  const float* ln_w = (const float*)d_in[1];
  const float* ln_b = (const float*)d_in[2];
  const float* embd = (const float*)d_in[3];
  float* out_q = (float*)d_out;
  float* out_idx = out_q + (size_t)M_TOT * 256;
  char* ws = (char*)d_ws;
  f16* kfrag = (f16*)(ws + WS_KFRAG);
  f16* vfrag = (f16*)(ws + WS_VFRAG);
  unsigned* count = (unsigned*)(ws + WS_COUNT);
  int* list = (int*)(ws + WS_LIST);
  float2* part = (float2*)(ws + WS_PART);
  float* embd_t = (float*)(ws + WS_EMBDT);

  prep_kernel<<<512, 256, 0, stream>>>(embd, kfrag, vfrag, embd_t, count);
  fused_kernel<<<512, 256, 0, stream>>>(input, ln_w, ln_b, kfrag, vfrag,
                                        out_q, out_idx, count, list);
  refine_part_kernel<<<256, 256, 0, stream>>>(input, ln_w, ln_b, embd_t,
                                              count, list, part);
  refine_merge_kernel<<<16, 256, 0, stream>>>(out_idx, count, list, part);
}